// Round 5
// baseline (407.795 us; speedup 1.0000x reference)
//
#include <hip/hip_runtime.h>
#include <math.h>

#define BLK 256
// bucketed CSR build: 512 dst-nodes per bucket
#define BKT_BITS 9
#define BKT (1<<BKT_BITS)
#define MAXNB 256
#define EB 8192   // edges per bin-block

typedef __attribute__((ext_vector_type(8))) short bf16x8;
typedef __attribute__((ext_vector_type(4))) float f32x4;

__device__ inline unsigned short f2b(float f){
  union { float f; unsigned int u; } v; v.f = f;
  unsigned int u = v.u;
  return (unsigned short)((u + 0x7FFF + ((u >> 16) & 1)) >> 16);
}
__device__ inline float b2f_lo(unsigned int u){
  union { unsigned int u; float f; } v; v.u = u << 16; return v.f;
}
__device__ inline float b2f_hi(unsigned int u){
  union { unsigned int u; float f; } v; v.u = u & 0xFFFF0000u; return v.f;
}
// packed 2xbf16 convert (RNE, same rounding as f2b) — 1 instr per 2 floats
__device__ inline unsigned pkbf(float lo, float hi){
  unsigned r;
  asm("v_cvt_pk_bf16_f32 %0, %1, %2" : "=v"(r) : "v"(lo), "v"(hi));
  return r;
}

// ---------------- CSR build (3 kernels) ----------------

// bucket histogram only — LDS atomics + ~196 global adds per block
__global__ __launch_bounds__(256)
void bhistA(const int* __restrict__ dst, int* __restrict__ bhist, int E, int NB){
  __shared__ int h[MAXNB];
  int t = threadIdx.x;
  for (int i=t;i<NB;i+=256) h[i]=0;
  __syncthreads();
  int base = blockIdx.x*EB;
  #pragma unroll
  for (int k=0;k<EB/256;k++){
    int idx = base + k*256 + t;
    if (idx < E) atomicAdd(&h[dst[idx]>>BKT_BITS], 1);
  }
  __syncthreads();
  for (int i=t;i<NB;i+=256) if (h[i]) atomicAdd(&bhist[i], h[i]);
}

// bin edges into buckets via LDS sort; packed 4B output (src<<9 | dst&511)
// bucket base offsets computed redundantly per block from bhist
__global__ __launch_bounds__(256)
void binC(const int* __restrict__ src, const int* __restrict__ dst,
          const int* __restrict__ bhist, int* __restrict__ bcur,
          unsigned int* __restrict__ bins, int E, int NB){
  __shared__ int hsc[MAXNB];
  __shared__ int lh[MAXNB];
  __shared__ int lofs[MAXNB];
  __shared__ int lcur[MAXNB];
  __shared__ int gres[MAXNB];
  __shared__ __attribute__((aligned(16))) int2 buf[EB];
  int t = threadIdx.x;
  int v0 = (t < NB) ? bhist[t] : 0;
  hsc[t] = v0;
  for (int i=t;i<NB;i+=256) lh[i]=0;
  __syncthreads();
  for (int off=1; off<MAXNB; off<<=1){
    int v = (t>=off)?hsc[t-off]:0;
    __syncthreads();
    hsc[t]+=v;
    __syncthreads();
  }
  int boff_t = hsc[t]-v0;
  int base = blockIdx.x*EB;
  #pragma unroll
  for (int k=0;k<EB/256;k++){
    int idx = base + k*256 + t;
    if (idx < E) atomicAdd(&lh[dst[idx]>>BKT_BITS], 1);
  }
  __syncthreads();
  if (t==0){ int run=0; for (int b=0;b<NB;b++){ lofs[b]=run; run+=lh[b]; } }
  __syncthreads();
  if (t<NB){
    lcur[t] = lofs[t];
    gres[t] = lh[t] ? (boff_t + atomicAdd(&bcur[t], lh[t])) : 0;
  }
  __syncthreads();
  #pragma unroll
  for (int k=0;k<EB/256;k++){
    int idx = base + k*256 + t;
    if (idx < E){
      int d = dst[idx];
      int p = atomicAdd(&lcur[d>>BKT_BITS], 1);
      buf[p] = make_int2(src[idx], d);
    }
  }
  __syncthreads();
  int total = E - base; if (total > EB) total = EB;
  for (int i=t; i<total; i+=256){
    int2 pr = buf[i];
    int b = pr.y>>BKT_BITS;
    bins[gres[b] + (i - lofs[b])] = ((unsigned)pr.x << BKT_BITS) | (unsigned)(pr.y & (BKT-1));
  }
}

// per-bucket: degree (LDS atomics) -> local 512-scan -> rowptr + dinv + col fill + self-loops.
// No global scan: rowptr[node] = sum(bhist[0..b)) + base + local_excl_scan(dcnt+1).
// W1 transpose/cvt as independent tail blocks.
__global__ __launch_bounds__(256)
void bfill_all(const unsigned int* __restrict__ bins, const int* __restrict__ bhist,
               int* __restrict__ rowptr, float* __restrict__ dinv, int* __restrict__ col,
               const float* __restrict__ W1, unsigned short* __restrict__ W1T,
               int N, int NB){
  int b = blockIdx.x;
  if (b >= NB){   // W1 transpose+cvt tail
    int t2 = (b - NB)*256 + threadIdx.x;
    if (t2 < 256*128){
      int k = t2 >> 7, n = t2 & 127;
      W1T[n*256 + k] = f2b(W1[t2]);
    }
    return;
  }
  __shared__ int dcnt[BKT];
  __shared__ int rp[BKT];
  __shared__ int cur[BKT];
  __shared__ int sscan[256];
  __shared__ int sboff;
  int t = threadIdx.x;
  // bucket edge base = sum bhist[0..b)  (parallel partial + LDS reduce)
  int partial = 0;
  for (int j=t; j<b; j+=256) partial += bhist[j];
  if (t==0) sboff = 0;
  dcnt[t] = 0; dcnt[t+256] = 0;
  __syncthreads();
  if (partial) atomicAdd(&sboff, partial);
  __syncthreads();
  int s = sboff, cnt = bhist[b];
  // degree count from bucket's bin run
  for (int i=t;i<cnt;i+=256) atomicAdd(&dcnt[bins[s+i] & (BKT-1)], 1);
  __syncthreads();
  // local exclusive scan of (deg+1) over 512 nodes (2/thread)
  int base = b<<BKT_BITS;
  int i0 = 2*t, i1 = 2*t+1;
  int d0 = dcnt[i0], d1 = dcnt[i1];
  int n0 = (base+i0 < N) ? d0+1 : 0;
  int n1 = (base+i1 < N) ? d1+1 : 0;
  int tsum = n0+n1;
  sscan[t] = tsum; __syncthreads();
  for (int off=1; off<256; off<<=1){
    int v = (t>=off)? sscan[t-off]:0;
    __syncthreads();
    sscan[t]+=v;
    __syncthreads();
  }
  int run = sscan[t]-tsum;
  int gstart = s + base;   // prior buckets: s edges + base self-loops
  int rp0 = gstart + run, rp1 = rp0 + n0;
  rp[i0] = rp0; rp[i1] = rp1;
  cur[i0] = 0;  cur[i1] = 0;
  if (base+i0 < N){
    rowptr[base+i0] = rp0;
    dinv[base+i0] = rsqrtf((float)(d0+1));
    if (base+i0 == N-1) rowptr[N] = rp0 + d0 + 1;
  }
  if (base+i1 < N){
    rowptr[base+i1] = rp1;
    dinv[base+i1] = rsqrtf((float)(d1+1));
    if (base+i1 == N-1) rowptr[N] = rp1 + d1 + 1;
  }
  __syncthreads();
  // fill col via LDS cursors (single-CU full-line writes)
  for (int i=t;i<cnt;i+=256){
    unsigned pk = bins[s+i];
    int ln = pk & (BKT-1);
    int slot = atomicAdd(&cur[ln], 1);
    col[rp[ln] + slot] = (int)(pk >> BKT_BITS);
  }
  __syncthreads();
  for (int i=t;i<BKT;i+=256){
    int node = base+i;
    if (node < N) col[rp[i] + dcnt[i]] = node;   // self-loop last
  }
}

// ---------------- GEMM1 (MFMA bf16): h1b[r] = dinv[r] * (x @ W1)[r], bf16 ----------------
// v4: v3's W-stationary barrier-free structure, now 512-thread blocks (8 waves x 32 rows
// = 256 rows/block). Grid 391 -> all blocks co-resident at 2/CU (128KB LDS), 12-16
// waves/CU vs v3's 8: doubles latency-hiding multiplex. Same depth-2 reg prefetch.

__global__ __launch_bounds__(512)
void gemm1_mfma(const float* __restrict__ X, const unsigned short* __restrict__ W1T,
                const float* __restrict__ dinv, unsigned short* __restrict__ H1B, int M){
  // 64 B-fragments: frag f = (ct = f>>3, kstep = f&7); per-lane 16B at f*512(shorts)+lane*8
  __shared__ __attribute__((aligned(16))) unsigned short wsh[64*512];
  const int tid = threadIdx.x;
  const int wave = tid >> 6, lane = tid & 63;
  const int quad = lane >> 4, l16 = lane & 15;

  // ---- stage W1T -> swizzled LDS frags (one time, 8 uint4 per thread) ----
  // frag content: lane holds W1T[n = ct*16 + l16][k = ts*32 + quad*8 .. +8]
  #pragma unroll
  for (int f0=0; f0<64; f0+=8){
    int f = f0 + wave;
    int ct = f >> 3, ts = f & 7;
    uint4 v = *(const uint4*)(W1T + (ct*16 + l16)*256 + ts*32 + quad*8);
    *(uint4*)(wsh + f*512 + lane*8) = v;
  }
  __syncthreads();

  const int row0 = blockIdx.x * 256 + wave * 32;
  int rA = row0 + l16;
  int rB = rA + 16;
  int rAc = (rA < M) ? rA : (M-1);
  int rBc = (rB < M) ? rB : (M-1);
  const float* xA = X + (size_t)rAc*256 + quad*8;
  const float* xB = X + (size_t)rBc*256 + quad*8;

  f32x4 acc[2][8];
  #pragma unroll
  for (int i=0;i<2;i++)
    #pragma unroll
    for (int j=0;j<8;j++) acc[i][j] = (f32x4){0.f,0.f,0.f,0.f};

  // depth-2 register prefetch of A fragments (2 rows x 32B per step)
  float4 pf[2][4];
  #pragma unroll
  for (int s=0;s<2;s++){
    pf[s][0] = *(const float4*)(xA + s*32);
    pf[s][1] = *(const float4*)(xA + s*32 + 4);
    pf[s][2] = *(const float4*)(xB + s*32);
    pf[s][3] = *(const float4*)(xB + s*32 + 4);
  }

  #pragma unroll
  for (int t=0; t<8; t++){
    const int cur = t & 1;
    // convert current slot -> bf16 A-frags (cols quad*8 .. +8 of k-step t)
    union { bf16x8 v; unsigned u[4]; } fa, fb;
    fa.u[0] = pkbf(pf[cur][0].x, pf[cur][0].y);
    fa.u[1] = pkbf(pf[cur][0].z, pf[cur][0].w);
    fa.u[2] = pkbf(pf[cur][1].x, pf[cur][1].y);
    fa.u[3] = pkbf(pf[cur][1].z, pf[cur][1].w);
    fb.u[0] = pkbf(pf[cur][2].x, pf[cur][2].y);
    fb.u[1] = pkbf(pf[cur][2].z, pf[cur][2].w);
    fb.u[2] = pkbf(pf[cur][3].x, pf[cur][3].y);
    fb.u[3] = pkbf(pf[cur][3].z, pf[cur][3].w);
    // issue loads for step t+2 (wait lands ~2 full steps later)
    if (t < 6){
      pf[cur][0] = *(const float4*)(xA + (t+2)*32);
      pf[cur][1] = *(const float4*)(xA + (t+2)*32 + 4);
      pf[cur][2] = *(const float4*)(xB + (t+2)*32);
      pf[cur][3] = *(const float4*)(xB + (t+2)*32 + 4);
    }
    #pragma unroll
    for (int ct=0; ct<8; ct++){
      bf16x8 bf = *(const bf16x8*)(wsh + (ct*8 + t)*512 + lane*8);
      acc[0][ct] = __builtin_amdgcn_mfma_f32_16x16x32_bf16(fa.v, bf, acc[0][ct], 0, 0, 0);
      acc[1][ct] = __builtin_amdgcn_mfma_f32_16x16x32_bf16(fb.v, bf, acc[1][ct], 0, 0, 0);
    }
  }

  #pragma unroll
  for (int rt=0; rt<2; rt++){
    int rbase = row0 + rt*16 + quad*4;
    #pragma unroll
    for (int rg=0; rg<4; rg++){
      int grow = rbase + rg;
      if (grow < M){
        float dv = dinv[grow];
        #pragma unroll
        for (int ct=0; ct<8; ct++)
          H1B[(size_t)grow*128 + ct*16 + l16] = f2b(dv * acc[rt][ct][rg]);
      }
    }
  }
}

// ---------------- agg1 (+ fused gemm2): wave/node gather -> relu(f32 r1) -> r1@W2 -> h2b ----
// Gather structure unchanged (4 edge-groups x 16 lanes x 16B, 16 edges/iter in flight).
// Epilogue now fuses the second dense layer: after the cross-group reduce every lane holds
// the f32 r1 partial for its 8 features (f = l16*8..+7). Group g computes class-pair g of
// r1@W2 (pair 4 computed redundantly by all groups), shfl-reduces over its 16 lanes, and
// lane 0 writes the packed bf16 pair into h2b. Eliminates r1b (25MB write + 25.6MB read)
// and the gemm2 kernel entirely; r1 stays f32 (more accurate than the old bf16 round-trip).

__device__ inline void acc8(float* a, uint4 u){
  a[0]+=b2f_lo(u.x); a[1]+=b2f_hi(u.x); a[2]+=b2f_lo(u.y); a[3]+=b2f_hi(u.y);
  a[4]+=b2f_lo(u.z); a[5]+=b2f_hi(u.z); a[6]+=b2f_lo(u.w); a[7]+=b2f_hi(u.w);
}

__global__ __launch_bounds__(256)
void agg1_kernel(const unsigned short* __restrict__ H1B, const int* __restrict__ rowptr,
                 const int* __restrict__ col, const float* __restrict__ dinv,
                 const float* __restrict__ b1, const float* __restrict__ W2,
                 unsigned int* __restrict__ H2B, int N){
  int node = blockIdx.x * 4 + (threadIdx.x >> 6);
  int lane = threadIdx.x & 63;
  int g   = lane >> 4;    // edge sub-group 0..3
  int l16 = lane & 15;    // 16B chunk within the 256B row
  if (node >= N) return;
  int s = rowptr[node], e = rowptr[node+1];
  float a[8];
  #pragma unroll
  for (int k=0;k<8;k++) a[k]=0.f;
  const char* hbase = (const char*)H1B + l16*16;
  int j = s;
  // 16 edges / iter: 4 independent dwordx4 gathers in flight
  for (; j+15 < e; j+=16){
    int c0 = col[j+g], c1 = col[j+4+g], c2 = col[j+8+g], c3 = col[j+12+g];
    uint4 u0 = *(const uint4*)(hbase + (((unsigned)c0) << 8));
    uint4 u1 = *(const uint4*)(hbase + (((unsigned)c1) << 8));
    uint4 u2 = *(const uint4*)(hbase + (((unsigned)c2) << 8));
    uint4 u3 = *(const uint4*)(hbase + (((unsigned)c3) << 8));
    acc8(a, u0); acc8(a, u1); acc8(a, u2); acc8(a, u3);
  }
  for (; j+7 < e; j+=8){
    int c0 = col[j+g], c1 = col[j+4+g];
    uint4 u0 = *(const uint4*)(hbase + (((unsigned)c0) << 8));
    uint4 u1 = *(const uint4*)(hbase + (((unsigned)c1) << 8));
    acc8(a, u0); acc8(a, u1);
  }
  {
    int rem = e - j;   // 0..7
    if (g < rem){
      int c0 = col[j+g];
      uint4 u0 = *(const uint4*)(hbase + (((unsigned)c0) << 8));
      acc8(a, u0);
    }
    if (g+4 < rem){
      int c1 = col[j+4+g];
      uint4 u1 = *(const uint4*)(hbase + (((unsigned)c1) << 8));
      acc8(a, u1);
    }
  }
  // reduce across the 4 edge-groups (lanes l16, l16+16, l16+32, l16+48 hold same features)
  #pragma unroll
  for (int k=0;k<8;k++){
    a[k] += __shfl_xor(a[k], 16);
    a[k] += __shfl_xor(a[k], 32);
  }
  // r1 = relu(dv*a + b1) in f32; feature f = l16*8+k (all lanes hold full sums)
  float dv = dinv[node];
  float4 bl = *(const float4*)(b1 + l16*8);
  float4 bh = *(const float4*)(b1 + l16*8 + 4);
  float r1v[8];
  r1v[0]=fmaxf(dv*a[0]+bl.x,0.f); r1v[1]=fmaxf(dv*a[1]+bl.y,0.f);
  r1v[2]=fmaxf(dv*a[2]+bl.z,0.f); r1v[3]=fmaxf(dv*a[3]+bl.w,0.f);
  r1v[4]=fmaxf(dv*a[4]+bh.x,0.f); r1v[5]=fmaxf(dv*a[5]+bh.y,0.f);
  r1v[6]=fmaxf(dv*a[6]+bh.z,0.f); r1v[7]=fmaxf(dv*a[7]+bh.w,0.f);
  // fused gemm2: group g -> class pair (2g, 2g+1); pair 4 (c8,c9) in all groups.
  // W2 is [128][10] row-major f32, L1/L2-hot (5KB).
  const float* w2row = W2 + (size_t)(l16*8)*10;
  float s0=0.f, s1=0.f, t0=0.f, t1=0.f;
  #pragma unroll
  for (int k=0;k<8;k++){
    float2 wg = *(const float2*)(w2row + k*10 + 2*g);
    float2 w4 = *(const float2*)(w2row + k*10 + 8);
    s0 += r1v[k]*wg.x; s1 += r1v[k]*wg.y;
    t0 += r1v[k]*w4.x; t1 += r1v[k]*w4.y;
  }
  #pragma unroll
  for (int m=1; m<16; m<<=1){
    s0 += __shfl_xor(s0, m); s1 += __shfl_xor(s1, m);
    t0 += __shfl_xor(t0, m); t1 += __shfl_xor(t1, m);
  }
  if (l16 == 0){
    H2B[(size_t)node*8 + g] = pkbf(dv*s0, dv*s1);
    if (g == 0) H2B[(size_t)node*8 + 4] = pkbf(dv*t0, dv*t1);
  }
}

// ---------------- agg2 + bias + log_softmax (2-wide, bf16 h2) ----------------

__global__ __launch_bounds__(256)
void agg2_softmax_kernel(const unsigned int* __restrict__ H2B, const int* __restrict__ rowptr,
                         const int* __restrict__ col, const float* __restrict__ dinv,
                         const float* __restrict__ b2, float* __restrict__ out, int N){
  int i = blockIdx.x*blockDim.x + threadIdx.x;
  if (i >= N) return;
  float acc[10], acc2[10];
  #pragma unroll
  for (int c=0;c<10;c++){ acc[c] = 0.f; acc2[c] = 0.f; }
  int s = rowptr[i], e = rowptr[i+1];
  int j = s;
  for (; j+1 < e; j += 2){
    const unsigned int* hA = H2B + (size_t)col[j]*8;
    const unsigned int* hB = H2B + (size_t)col[j+1]*8;
    uint4 a = *(const uint4*)hA; unsigned a4 = hA[4];
    uint4 b = *(const uint4*)hB; unsigned b4 = hB[4];
    acc[0]+=b2f_lo(a.x); acc[1]+=b2f_hi(a.x); acc[2]+=b2f_lo(a.y); acc[3]+=b2f_hi(a.y);
    acc[4]+=b2f_lo(a.z); acc[5]+=b2f_hi(a.z); acc[6]+=b2f_lo(a.w); acc[7]+=b2f_hi(a.w);
    acc[8]+=b2f_lo(a4);  acc[9]+=b2f_hi(a4);
    acc2[0]+=b2f_lo(b.x); acc2[1]+=b2f_hi(b.x); acc2[2]+=b2f_lo(b.y); acc2[3]+=b2f_hi(b.y);
    acc2[4]+=b2f_lo(b.z); acc2[5]+=b2f_hi(b.z); acc2[6]+=b2f_lo(b.w); acc2[7]+=b2f_hi(b.w);
    acc2[8]+=b2f_lo(b4);  acc2[9]+=b2f_hi(b4);
  }
  if (j < e){
    const unsigned int* hA = H2B + (size_t)col[j]*8;
    uint4 a = *(const uint4*)hA; unsigned a4 = hA[4];
    acc[0]+=b2f_lo(a.x); acc[1]+=b2f_hi(a.x); acc[2]+=b2f_lo(a.y); acc[3]+=b2f_hi(a.y);
    acc[4]+=b2f_lo(a.z); acc[5]+=b2f_hi(a.z); acc[6]+=b2f_lo(a.w); acc[7]+=b2f_hi(a.w);
    acc[8]+=b2f_lo(a4);  acc[9]+=b2f_hi(a4);
  }
  float dv = dinv[i];
  #pragma unroll
  for (int f=0;f<10;f++) acc[f] = dv*(acc[f] + acc2[f]) + b2[f];
  float m = acc[0];
  #pragma unroll
  for (int f=1;f<10;f++) m = fmaxf(m, acc[f]);
  float sum = 0.f;
  #pragma unroll
  for (int f=0;f<10;f++) sum += expf(acc[f] - m);
  float lg = m + logf(sum);
  #pragma unroll
  for (int f=0;f<10;f++) out[(size_t)i*10 + f] = acc[f] - lg;
}

// ---------------- launch ----------------

extern "C" void kernel_launch(void* const* d_in, const int* in_sizes, int n_in,
                              void* d_out, int out_size, void* d_ws, size_t ws_size,
                              hipStream_t stream){
  const float* x    = (const float*)d_in[0];
  const int*   ei   = (const int*)d_in[1];
  const float* W1   = (const float*)d_in[2];
  const float* b1   = (const float*)d_in[3];
  const float* W2   = (const float*)d_in[4];
  const float* b2   = (const float*)d_in[5];
  float* out = (float*)d_out;

  const int N = in_sizes[0] / 256;   // 100000
  const int E = in_sizes[1] / 2;     // 1600000
  const int NNZ = E + N;
  const int* src = ei;
  const int* dst = ei + E;
  const int NB = (N + BKT - 1) >> BKT_BITS;   // 196
  const int WB = 128;                         // wcvt tail blocks

  char* ws = (char*)d_ws;
  size_t off = 0;
  auto alloc = [&](size_t bytes)->char*{
    char* p = ws + off;
    off = (off + bytes + 255) & ~(size_t)255;
    return p;
  };
  // zero region: bhist | bcur (single small memset)
  int*   zreg   = (int*)  alloc((size_t)(MAXNB*2)*4);
  int*   bhist  = zreg;
  int*   bcur   = zreg + MAXNB;
  float* dinv   = (float*)alloc((size_t)N*4);
  int*   rowptr = (int*)  alloc((size_t)(N+1)*4);
  unsigned int* bins = (unsigned int*)alloc((size_t)E*4);
  int*   col    = (int*)  alloc((size_t)NNZ*4);
  unsigned short* w1t = (unsigned short*)alloc((size_t)128*256*2);
  unsigned short* h1b = (unsigned short*)alloc((size_t)N*128*2);
  unsigned int*   h2b = (unsigned int*)  alloc((size_t)N*8*4);
  (void)ws_size;

  hipMemsetAsync(zreg, 0, (size_t)(MAXNB*2)*4, stream);

  const int NCB = (E + EB - 1) / EB;

  bhistA<<<NCB, 256, 0, stream>>>(dst, bhist, E, NB);
  binC<<<NCB, 256, 0, stream>>>(src, dst, bhist, bcur, bins, E, NB);
  bfill_all<<<NB + WB, 256, 0, stream>>>(bins, bhist, rowptr, dinv, col, W1, w1t, N, NB);

  gemm1_mfma<<<(N+255)/256, 512, 0, stream>>>(x, w1t, dinv, h1b, N);
  agg1_kernel<<<(N+3)/4, 256, 0, stream>>>(h1b, rowptr, col, dinv, b1, W2, h2b, N);
  agg2_softmax_kernel<<<(N+BLK-1)/BLK, BLK, 0, stream>>>(h2b, rowptr, col, dinv, b2, out, N);
}

// Round 6
// 317.104 us; speedup vs baseline: 1.2860x; 1.2860x over previous
//
#include <hip/hip_runtime.h>
#include <math.h>

#define BLK 256
// bucketed CSR build: 512 dst-nodes per bucket
#define BKT_BITS 9
#define BKT (1<<BKT_BITS)
#define MAXNB 256
#define EB 8192      // edges per bin-block
#define BSTRIDE 16384 // per-bucket slot stride in bins (mean fill 8192, 91-sigma safe)

typedef __attribute__((ext_vector_type(8))) short bf16x8;
typedef __attribute__((ext_vector_type(4))) float f32x4;

__device__ inline unsigned short f2b(float f){
  union { float f; unsigned int u; } v; v.f = f;
  unsigned int u = v.u;
  return (unsigned short)((u + 0x7FFF + ((u >> 16) & 1)) >> 16);
}
__device__ inline float b2f_lo(unsigned int u){
  union { unsigned int u; float f; } v; v.u = u << 16; return v.f;
}
__device__ inline float b2f_hi(unsigned int u){
  union { unsigned int u; float f; } v; v.u = u & 0xFFFF0000u; return v.f;
}
// packed 2xbf16 convert (RNE, same rounding as f2b) — 1 instr per 2 floats
__device__ inline unsigned pkbf(float lo, float hi){
  unsigned r;
  asm("v_cvt_pk_bf16_f32 %0, %1, %2" : "=v"(r) : "v"(lo), "v"(hi));
  return r;
}

// ---------------- CSR build (2 kernels; bhistA eliminated) ----------------

// bin edges into fixed-stride bucket regions. Per-block: int4 edge loads, LDS histogram,
// parallel 256-scan, global reservation via atomicAdd(bcnt) (bcnt also = final counts),
// LDS sort into buf, full-line packed writes to bins[b*BSTRIDE + ...].
__global__ __launch_bounds__(256)
void binC(const int* __restrict__ src, const int* __restrict__ dst,
          int* __restrict__ bcnt, unsigned int* __restrict__ bins, int E, int NB){
  __shared__ int lh[MAXNB];
  __shared__ int lofs[MAXNB];
  __shared__ int lcur[MAXNB];
  __shared__ int gres[MAXNB];
  __shared__ int sscan[256];
  __shared__ __attribute__((aligned(16))) int2 buf[EB];
  int t = threadIdx.x;
  for (int i=t;i<MAXNB;i+=256) lh[i]=0;
  __syncthreads();
  int base = blockIdx.x*EB;
  // histogram: 8 x int4 loads per thread (E % 4 == 0)
  #pragma unroll
  for (int k=0;k<EB/1024;k++){
    int idx = base + (k*256 + t)*4;
    if (idx < E){
      int4 d = *(const int4*)(dst + idx);
      atomicAdd(&lh[d.x>>BKT_BITS],1);
      atomicAdd(&lh[d.y>>BKT_BITS],1);
      atomicAdd(&lh[d.z>>BKT_BITS],1);
      atomicAdd(&lh[d.w>>BKT_BITS],1);
    }
  }
  __syncthreads();
  // parallel exclusive scan of lh -> lofs
  int v0 = lh[t];
  sscan[t] = v0; __syncthreads();
  for (int off=1; off<256; off<<=1){
    int v = (t>=off)? sscan[t-off]:0;
    __syncthreads();
    sscan[t]+=v;
    __syncthreads();
  }
  lofs[t] = sscan[t]-v0;
  lcur[t] = sscan[t]-v0;
  if (t < NB)
    gres[t] = lh[t] ? (t*BSTRIDE + atomicAdd(&bcnt[t], lh[t])) : 0;
  __syncthreads();
  // scatter into LDS buf grouped by bucket
  #pragma unroll
  for (int k=0;k<EB/1024;k++){
    int idx = base + (k*256 + t)*4;
    if (idx < E){
      int4 s4 = *(const int4*)(src + idx);
      int4 d4 = *(const int4*)(dst + idx);
      int p;
      p = atomicAdd(&lcur[d4.x>>BKT_BITS],1); buf[p] = make_int2(s4.x,d4.x);
      p = atomicAdd(&lcur[d4.y>>BKT_BITS],1); buf[p] = make_int2(s4.y,d4.y);
      p = atomicAdd(&lcur[d4.z>>BKT_BITS],1); buf[p] = make_int2(s4.z,d4.z);
      p = atomicAdd(&lcur[d4.w>>BKT_BITS],1); buf[p] = make_int2(s4.w,d4.w);
    }
  }
  __syncthreads();
  int total = E - base; if (total > EB) total = EB;
  for (int i=t; i<total; i+=256){
    int2 pr = buf[i];
    int b = pr.y>>BKT_BITS;
    bins[gres[b] + (i - lofs[b])] = ((unsigned)pr.x << BKT_BITS) | (unsigned)(pr.y & (BKT-1));
  }
}

// per-bucket: degree (LDS atomics) -> local 512-scan -> rowptr + dinv + col fill + self-loops.
// Bucket b's edges live at bins[b*BSTRIDE .. +bcnt[b]); global edge base = sum bcnt[0..b).
// W1 transpose/cvt as independent tail blocks.
__global__ __launch_bounds__(256)
void bfill_all(const unsigned int* __restrict__ bins, const int* __restrict__ bcnt,
               int* __restrict__ rowptr, float* __restrict__ dinv, int* __restrict__ col,
               const float* __restrict__ W1, unsigned short* __restrict__ W1T,
               int N, int NB){
  int b = blockIdx.x;
  if (b >= NB){   // W1 transpose+cvt tail
    int t2 = (b - NB)*256 + threadIdx.x;
    if (t2 < 256*128){
      int k = t2 >> 7, n = t2 & 127;
      W1T[n*256 + k] = f2b(W1[t2]);
    }
    return;
  }
  __shared__ int dcnt[BKT];
  __shared__ int rp[BKT];
  __shared__ int cur[BKT];
  __shared__ int sscan[256];
  __shared__ int sboff;
  int t = threadIdx.x;
  // bucket edge base = sum bcnt[0..b)  (parallel partial + LDS reduce)
  int partial = 0;
  for (int j=t; j<b; j+=256) partial += bcnt[j];
  if (t==0) sboff = 0;
  dcnt[t] = 0; dcnt[t+256] = 0;
  __syncthreads();
  if (partial) atomicAdd(&sboff, partial);
  __syncthreads();
  int s = sboff, cnt = bcnt[b];
  const unsigned int* mybins = bins + (size_t)b*BSTRIDE;
  // degree count from bucket's bin run
  for (int i=t;i<cnt;i+=256) atomicAdd(&dcnt[mybins[i] & (BKT-1)], 1);
  __syncthreads();
  // local exclusive scan of (deg+1) over 512 nodes (2/thread)
  int base = b<<BKT_BITS;
  int i0 = 2*t, i1 = 2*t+1;
  int d0 = dcnt[i0], d1 = dcnt[i1];
  int n0 = (base+i0 < N) ? d0+1 : 0;
  int n1 = (base+i1 < N) ? d1+1 : 0;
  int tsum = n0+n1;
  sscan[t] = tsum; __syncthreads();
  for (int off=1; off<256; off<<=1){
    int v = (t>=off)? sscan[t-off]:0;
    __syncthreads();
    sscan[t]+=v;
    __syncthreads();
  }
  int run = sscan[t]-tsum;
  int gstart = s + base;   // prior buckets: s edges + base self-loops
  int rp0 = gstart + run, rp1 = rp0 + n0;
  rp[i0] = rp0; rp[i1] = rp1;
  cur[i0] = 0;  cur[i1] = 0;
  if (base+i0 < N){
    rowptr[base+i0] = rp0;
    dinv[base+i0] = rsqrtf((float)(d0+1));
    if (base+i0 == N-1) rowptr[N] = rp0 + d0 + 1;
  }
  if (base+i1 < N){
    rowptr[base+i1] = rp1;
    dinv[base+i1] = rsqrtf((float)(d1+1));
    if (base+i1 == N-1) rowptr[N] = rp1 + d1 + 1;
  }
  __syncthreads();
  // fill col via LDS cursors (single-CU full-line writes)
  for (int i=t;i<cnt;i+=256){
    unsigned pk = mybins[i];
    int ln = pk & (BKT-1);
    int slot = atomicAdd(&cur[ln], 1);
    col[rp[ln] + slot] = (int)(pk >> BKT_BITS);
  }
  __syncthreads();
  for (int i=t;i<BKT;i+=256){
    int node = base+i;
    if (node < N) col[rp[i] + dcnt[i]] = node;   // self-loop last
  }
}

// ---------------- GEMM1 (MFMA bf16): h1b[r] = dinv[r] * (x @ W1)[r], bf16 ----------------
// v4: W-stationary barrier-free structure, 512-thread blocks (8 waves x 32 rows
// = 256 rows/block). Grid 391 -> all blocks co-resident at 2/CU (128KB LDS), 12-16
// waves/CU: latency-hiding multiplex. Depth-2 reg prefetch, cvt_pk bf16.

__global__ __launch_bounds__(512)
void gemm1_mfma(const float* __restrict__ X, const unsigned short* __restrict__ W1T,
                const float* __restrict__ dinv, unsigned short* __restrict__ H1B, int M){
  // 64 B-fragments: frag f = (ct = f>>3, kstep = f&7); per-lane 16B at f*512(shorts)+lane*8
  __shared__ __attribute__((aligned(16))) unsigned short wsh[64*512];
  const int tid = threadIdx.x;
  const int wave = tid >> 6, lane = tid & 63;
  const int quad = lane >> 4, l16 = lane & 15;

  // ---- stage W1T -> swizzled LDS frags (one time, 8 uint4 per thread) ----
  // frag content: lane holds W1T[n = ct*16 + l16][k = ts*32 + quad*8 .. +8]
  #pragma unroll
  for (int f0=0; f0<64; f0+=8){
    int f = f0 + wave;
    int ct = f >> 3, ts = f & 7;
    uint4 v = *(const uint4*)(W1T + (ct*16 + l16)*256 + ts*32 + quad*8);
    *(uint4*)(wsh + f*512 + lane*8) = v;
  }
  __syncthreads();

  const int row0 = blockIdx.x * 256 + wave * 32;
  int rA = row0 + l16;
  int rB = rA + 16;
  int rAc = (rA < M) ? rA : (M-1);
  int rBc = (rB < M) ? rB : (M-1);
  const float* xA = X + (size_t)rAc*256 + quad*8;
  const float* xB = X + (size_t)rBc*256 + quad*8;

  f32x4 acc[2][8];
  #pragma unroll
  for (int i=0;i<2;i++)
    #pragma unroll
    for (int j=0;j<8;j++) acc[i][j] = (f32x4){0.f,0.f,0.f,0.f};

  // depth-2 register prefetch of A fragments (2 rows x 32B per step)
  float4 pf[2][4];
  #pragma unroll
  for (int s=0;s<2;s++){
    pf[s][0] = *(const float4*)(xA + s*32);
    pf[s][1] = *(const float4*)(xA + s*32 + 4);
    pf[s][2] = *(const float4*)(xB + s*32);
    pf[s][3] = *(const float4*)(xB + s*32 + 4);
  }

  #pragma unroll
  for (int t=0; t<8; t++){
    const int cur = t & 1;
    // convert current slot -> bf16 A-frags (cols quad*8 .. +8 of k-step t)
    union { bf16x8 v; unsigned u[4]; } fa, fb;
    fa.u[0] = pkbf(pf[cur][0].x, pf[cur][0].y);
    fa.u[1] = pkbf(pf[cur][0].z, pf[cur][0].w);
    fa.u[2] = pkbf(pf[cur][1].x, pf[cur][1].y);
    fa.u[3] = pkbf(pf[cur][1].z, pf[cur][1].w);
    fb.u[0] = pkbf(pf[cur][2].x, pf[cur][2].y);
    fb.u[1] = pkbf(pf[cur][2].z, pf[cur][2].w);
    fb.u[2] = pkbf(pf[cur][3].x, pf[cur][3].y);
    fb.u[3] = pkbf(pf[cur][3].z, pf[cur][3].w);
    // issue loads for step t+2 (wait lands ~2 full steps later)
    if (t < 6){
      pf[cur][0] = *(const float4*)(xA + (t+2)*32);
      pf[cur][1] = *(const float4*)(xA + (t+2)*32 + 4);
      pf[cur][2] = *(const float4*)(xB + (t+2)*32);
      pf[cur][3] = *(const float4*)(xB + (t+2)*32 + 4);
    }
    #pragma unroll
    for (int ct=0; ct<8; ct++){
      bf16x8 bf = *(const bf16x8*)(wsh + (ct*8 + t)*512 + lane*8);
      acc[0][ct] = __builtin_amdgcn_mfma_f32_16x16x32_bf16(fa.v, bf, acc[0][ct], 0, 0, 0);
      acc[1][ct] = __builtin_amdgcn_mfma_f32_16x16x32_bf16(fb.v, bf, acc[1][ct], 0, 0, 0);
    }
  }

  #pragma unroll
  for (int rt=0; rt<2; rt++){
    int rbase = row0 + rt*16 + quad*4;
    #pragma unroll
    for (int rg=0; rg<4; rg++){
      int grow = rbase + rg;
      if (grow < M){
        float dv = dinv[grow];
        #pragma unroll
        for (int ct=0; ct<8; ct++)
          H1B[(size_t)grow*128 + ct*16 + l16] = f2b(dv * acc[rt][ct][rg]);
      }
    }
  }
}

// ---------------- agg1: wave/node gather, 4 edge-groups x 16 lanes x 16B ----------------
// (round-4 measured version — fusion of gemm2 reverted: it halved gather throughput)

__device__ inline void acc8(float* a, uint4 u){
  a[0]+=b2f_lo(u.x); a[1]+=b2f_hi(u.x); a[2]+=b2f_lo(u.y); a[3]+=b2f_hi(u.y);
  a[4]+=b2f_lo(u.z); a[5]+=b2f_hi(u.z); a[6]+=b2f_lo(u.w); a[7]+=b2f_hi(u.w);
}

__global__ __launch_bounds__(256)
void agg1_kernel(const unsigned short* __restrict__ H1B, const int* __restrict__ rowptr,
                 const int* __restrict__ col, const float* __restrict__ dinv,
                 const float* __restrict__ b1, unsigned int* __restrict__ R1B, int N){
  int node = blockIdx.x * 4 + (threadIdx.x >> 6);
  int lane = threadIdx.x & 63;
  int g   = lane >> 4;    // edge sub-group 0..3
  int l16 = lane & 15;    // 16B chunk within the 256B row
  if (node >= N) return;
  int s = rowptr[node], e = rowptr[node+1];
  float a[8];
  #pragma unroll
  for (int k=0;k<8;k++) a[k]=0.f;
  const char* hbase = (const char*)H1B + l16*16;
  int j = s;
  // 16 edges / iter: 4 independent dwordx4 gathers in flight
  for (; j+15 < e; j+=16){
    int c0 = col[j+g], c1 = col[j+4+g], c2 = col[j+8+g], c3 = col[j+12+g];
    uint4 u0 = *(const uint4*)(hbase + (((unsigned)c0) << 8));
    uint4 u1 = *(const uint4*)(hbase + (((unsigned)c1) << 8));
    uint4 u2 = *(const uint4*)(hbase + (((unsigned)c2) << 8));
    uint4 u3 = *(const uint4*)(hbase + (((unsigned)c3) << 8));
    acc8(a, u0); acc8(a, u1); acc8(a, u2); acc8(a, u3);
  }
  for (; j+7 < e; j+=8){
    int c0 = col[j+g], c1 = col[j+4+g];
    uint4 u0 = *(const uint4*)(hbase + (((unsigned)c0) << 8));
    uint4 u1 = *(const uint4*)(hbase + (((unsigned)c1) << 8));
    acc8(a, u0); acc8(a, u1);
  }
  {
    int rem = e - j;   // 0..7
    if (g < rem){
      int c0 = col[j+g];
      uint4 u0 = *(const uint4*)(hbase + (((unsigned)c0) << 8));
      acc8(a, u0);
    }
    if (g+4 < rem){
      int c1 = col[j+4+g];
      uint4 u1 = *(const uint4*)(hbase + (((unsigned)c1) << 8));
      acc8(a, u1);
    }
  }
  // reduce across the 4 edge-groups (lanes l16, l16+16, l16+32, l16+48 hold same features)
  #pragma unroll
  for (int k=0;k<8;k++){
    a[k] += __shfl_xor(a[k], 16);
    a[k] += __shfl_xor(a[k], 32);
  }
  if (g == 0){
    float dv = dinv[node];
    float4 bl = *(const float4*)(b1 + l16*8);
    float4 bh = *(const float4*)(b1 + l16*8 + 4);
    float f0, f1;
    unsigned int o0, o1, o2, o3;
    f0 = fmaxf(dv*a[0] + bl.x, 0.f); f1 = fmaxf(dv*a[1] + bl.y, 0.f);
    o0 = (unsigned)f2b(f0) | ((unsigned)f2b(f1) << 16);
    f0 = fmaxf(dv*a[2] + bl.z, 0.f); f1 = fmaxf(dv*a[3] + bl.w, 0.f);
    o1 = (unsigned)f2b(f0) | ((unsigned)f2b(f1) << 16);
    f0 = fmaxf(dv*a[4] + bh.x, 0.f); f1 = fmaxf(dv*a[5] + bh.y, 0.f);
    o2 = (unsigned)f2b(f0) | ((unsigned)f2b(f1) << 16);
    f0 = fmaxf(dv*a[6] + bh.z, 0.f); f1 = fmaxf(dv*a[7] + bh.w, 0.f);
    o3 = (unsigned)f2b(f0) | ((unsigned)f2b(f1) << 16);
    *(uint4*)(R1B + (size_t)node*64 + l16*4) = make_uint4(o0, o1, o2, o3);
  }
}

// ---------------- GEMM2: h2b[r] = bf16( dinv[r] * (r1[r] @ W2) ), packed 32B stride ----------------

__global__ __launch_bounds__(256)
void gemm2_kernel(const unsigned int* __restrict__ R1B, const float* __restrict__ W2,
                  const float* __restrict__ dinv, unsigned int* __restrict__ H2B, int M){
  __shared__ float w2s[128*10];
  for (int i = threadIdx.x; i < 128*10; i += blockDim.x) w2s[i] = W2[i];
  __syncthreads();
  int r = blockIdx.x*blockDim.x + threadIdx.x;
  if (r >= M) return;
  float acc[10];
  #pragma unroll
  for (int c=0;c<10;c++) acc[c] = 0.f;
  const unsigned int* row = R1B + (size_t)r*64;
  for (int k=0;k<64;k+=4){
    uint4 u = *(const uint4*)(row + k);
    float f0 = b2f_lo(u.x), f1 = b2f_hi(u.x);
    float f2 = b2f_lo(u.y), f3 = b2f_hi(u.y);
    float f4 = b2f_lo(u.z), f5 = b2f_hi(u.z);
    float f6 = b2f_lo(u.w), f7 = b2f_hi(u.w);
    #pragma unroll
    for (int c=0;c<10;c++){
      acc[c] += f0*w2s[(2*k+0)*10+c] + f1*w2s[(2*k+1)*10+c]
              + f2*w2s[(2*k+2)*10+c] + f3*w2s[(2*k+3)*10+c]
              + f4*w2s[(2*k+4)*10+c] + f5*w2s[(2*k+5)*10+c]
              + f6*w2s[(2*k+6)*10+c] + f7*w2s[(2*k+7)*10+c];
    }
  }
  float dv = dinv[r];
  unsigned int p[5];
  #pragma unroll
  for (int c=0;c<5;c++)
    p[c] = (unsigned)f2b(dv*acc[2*c]) | ((unsigned)f2b(dv*acc[2*c+1]) << 16);
  unsigned int* op = H2B + (size_t)r*8;
  *(uint4*)op = make_uint4(p[0],p[1],p[2],p[3]);
  op[4] = p[4];
}

// ---------------- agg2 + bias + log_softmax (2-wide, bf16 h2) ----------------

__global__ __launch_bounds__(256)
void agg2_softmax_kernel(const unsigned int* __restrict__ H2B, const int* __restrict__ rowptr,
                         const int* __restrict__ col, const float* __restrict__ dinv,
                         const float* __restrict__ b2, float* __restrict__ out, int N){
  int i = blockIdx.x*blockDim.x + threadIdx.x;
  if (i >= N) return;
  float acc[10], acc2[10];
  #pragma unroll
  for (int c=0;c<10;c++){ acc[c] = 0.f; acc2[c] = 0.f; }
  int s = rowptr[i], e = rowptr[i+1];
  int j = s;
  for (; j+1 < e; j += 2){
    const unsigned int* hA = H2B + (size_t)col[j]*8;
    const unsigned int* hB = H2B + (size_t)col[j+1]*8;
    uint4 a = *(const uint4*)hA; unsigned a4 = hA[4];
    uint4 b = *(const uint4*)hB; unsigned b4 = hB[4];
    acc[0]+=b2f_lo(a.x); acc[1]+=b2f_hi(a.x); acc[2]+=b2f_lo(a.y); acc[3]+=b2f_hi(a.y);
    acc[4]+=b2f_lo(a.z); acc[5]+=b2f_hi(a.z); acc[6]+=b2f_lo(a.w); acc[7]+=b2f_hi(a.w);
    acc[8]+=b2f_lo(a4);  acc[9]+=b2f_hi(a4);
    acc2[0]+=b2f_lo(b.x); acc2[1]+=b2f_hi(b.x); acc2[2]+=b2f_lo(b.y); acc2[3]+=b2f_hi(b.y);
    acc2[4]+=b2f_lo(b.z); acc2[5]+=b2f_hi(b.z); acc2[6]+=b2f_lo(b.w); acc2[7]+=b2f_hi(b.w);
    acc2[8]+=b2f_lo(b4);  acc2[9]+=b2f_hi(b4);
  }
  if (j < e){
    const unsigned int* hA = H2B + (size_t)col[j]*8;
    uint4 a = *(const uint4*)hA; unsigned a4 = hA[4];
    acc[0]+=b2f_lo(a.x); acc[1]+=b2f_hi(a.x); acc[2]+=b2f_lo(a.y); acc[3]+=b2f_hi(a.y);
    acc[4]+=b2f_lo(a.z); acc[5]+=b2f_hi(a.z); acc[6]+=b2f_lo(a.w); acc[7]+=b2f_hi(a.w);
    acc[8]+=b2f_lo(a4);  acc[9]+=b2f_hi(a4);
  }
  float dv = dinv[i];
  #pragma unroll
  for (int f=0;f<10;f++) acc[f] = dv*(acc[f] + acc2[f]) + b2[f];
  float m = acc[0];
  #pragma unroll
  for (int f=1;f<10;f++) m = fmaxf(m, acc[f]);
  float sum = 0.f;
  #pragma unroll
  for (int f=0;f<10;f++) sum += expf(acc[f] - m);
  float lg = m + logf(sum);
  #pragma unroll
  for (int f=0;f<10;f++) out[(size_t)i*10 + f] = acc[f] - lg;
}

// ---------------- launch ----------------

extern "C" void kernel_launch(void* const* d_in, const int* in_sizes, int n_in,
                              void* d_out, int out_size, void* d_ws, size_t ws_size,
                              hipStream_t stream){
  const float* x    = (const float*)d_in[0];
  const int*   ei   = (const int*)d_in[1];
  const float* W1   = (const float*)d_in[2];
  const float* b1   = (const float*)d_in[3];
  const float* W2   = (const float*)d_in[4];
  const float* b2   = (const float*)d_in[5];
  float* out = (float*)d_out;

  const int N = in_sizes[0] / 256;   // 100000
  const int E = in_sizes[1] / 2;     // 1600000
  const int NNZ = E + N;
  const int* src = ei;
  const int* dst = ei + E;
  const int NB = (N + BKT - 1) >> BKT_BITS;   // 196
  const int WB = 128;                         // wcvt tail blocks

  char* ws = (char*)d_ws;
  size_t off = 0;
  auto alloc = [&](size_t bytes)->char*{
    char* p = ws + off;
    off = (off + bytes + 255) & ~(size_t)255;
    return p;
  };
  int*   bcnt   = (int*)  alloc((size_t)MAXNB*4);   // zeroed; reservation + final counts
  float* dinv   = (float*)alloc((size_t)N*4);
  int*   rowptr = (int*)  alloc((size_t)(N+1)*4);
  unsigned int* bins = (unsigned int*)alloc((size_t)NB*BSTRIDE*4);
  int*   col    = (int*)  alloc((size_t)NNZ*4);
  unsigned short* w1t = (unsigned short*)alloc((size_t)128*256*2);
  unsigned short* h1b = (unsigned short*)alloc((size_t)N*128*2);
  unsigned int*   r1b = (unsigned int*)  alloc((size_t)N*64*4);
  unsigned int*   h2b = (unsigned int*)  alloc((size_t)N*8*4);
  (void)ws_size;

  hipMemsetAsync(bcnt, 0, (size_t)MAXNB*4, stream);

  const int NCB = (E + EB - 1) / EB;

  binC<<<NCB, 256, 0, stream>>>(src, dst, bcnt, bins, E, NB);
  bfill_all<<<NB + WB, 256, 0, stream>>>(bins, bcnt, rowptr, dinv, col, W1, w1t, N, NB);

  gemm1_mfma<<<(N+255)/256, 512, 0, stream>>>(x, w1t, dinv, h1b, N);
  agg1_kernel<<<(N+3)/4, 256, 0, stream>>>(h1b, rowptr, col, dinv, b1, r1b, N);
  gemm2_kernel<<<(N+BLK-1)/BLK, BLK, 0, stream>>>(r1b, W2, dinv, h2b, N);
  agg2_softmax_kernel<<<(N+BLK-1)/BLK, BLK, 0, stream>>>(h2b, rowptr, col, dinv, b2, out, N);
}